// Round 1
// baseline (1116.482 us; speedup 1.0000x reference)
//
#include <hip/hip_runtime.h>
#include <hip/hip_bf16.h>
#include <stdint.h>

typedef float f32x4 __attribute__((ext_vector_type(4)));
typedef short bf16x8 __attribute__((ext_vector_type(8)));

#define ARITY 8
#define DIM 384

__device__ __forceinline__ ushort to_bf16(float f) {
    union { float f; uint32_t u; } v; v.f = f;
    uint32_t u = v.u;
    return (ushort)((u + 0x7fffu + ((u >> 16) & 1u)) >> 16);   // RNE
}
__device__ __forceinline__ float sigmoid_(float x) { return 1.0f / (1.0f + __expf(-x)); }
__device__ __forceinline__ float tanh_(float x)    { return 1.0f - 2.0f / (__expf(2.0f * x) + 1.0f); }

// Build swizzled concat weight W'[g][k] = (k<384 ? w_ih[g][k] : w_hh[g][k-384]), bf16,
// laid out so a B-fragment load is one coalesced dwordx4 per lane:
//   dst[((tile*24 + kc)*64 + quad*16 + (g&15))*8 + j]  for k = kc*32 + quad*8 + j
__global__ void prep_w(const float* __restrict__ w_ih, const float* __restrict__ w_hh,
                       ushort* __restrict__ wswz) {
    int tid = blockIdx.x * blockDim.x + threadIdx.x;   // 1152 * 96
    if (tid >= 1152 * 96) return;
    int g  = tid / 96;
    int k  = (tid % 96) * 8;
    int kc = k >> 5;
    int q  = (k >> 3) & 3;
    int tile = g >> 4;
    int lane = q * 16 + (g & 15);
    ushort* dst = wswz + ((size_t)(tile * 24 + kc) * 64 + lane) * 8;
    const float* src = (k < 384) ? (w_ih + (size_t)g * 384 + k)
                                 : (w_hh + (size_t)g * 384 + (k - 384));
#pragma unroll
    for (int j = 0; j < 8; ++j) dst[j] = to_bf16(src[j]);
}

// Leaf embeddings -> bf16 x buffer
__global__ void embed_gather(const int* __restrict__ tok, const float* __restrict__ table,
                             ushort* __restrict__ xleaf, int n_leaves) {
    int tid = blockIdx.x * blockDim.x + threadIdx.x;   // n_leaves * 48
    if (tid >= n_leaves * 48) return;
    int leaf = tid / 48, i = tid % 48;
    const float* src = table + (size_t)tok[leaf] * 384 + i * 8;
    ushort* dst = xleaf + (size_t)leaf * 384 + i * 8;
#pragma unroll
    for (int j = 0; j < 8; ++j) dst[j] = to_bf16(src[j]);
}

// One tree level, fused over the 8 GRU steps. Block = 256 thr (4 waves) = 16 parents.
// Wave w owns r/z gate tiles [w*12, w*12+12) (gates w*192..) and n-tiles 48+w*6.. (d = w*96..).
__global__ __launch_bounds__(256, 2)
void level_kernel(const ushort* __restrict__ Xc, const float* __restrict__ Hc,
                  const ushort* __restrict__ W, const float* __restrict__ b_ih,
                  const float* __restrict__ b_hh, ushort* __restrict__ Xo,
                  float* __restrict__ Ho, float* __restrict__ fout, int P) {
    __shared__ alignas(16) ushort A[16][776];   // [parent][k] bf16: k<384 = x_t, k>=384 = h (+8 pad)
    __shared__ float RZ[16][769];               // sigmoid(r) at [m][d], sigmoid(z) at [m][384+d]

    const int tid  = threadIdx.x;
    const int wave = tid >> 6, lane = tid & 63;
    const int quad = lane >> 4, col = lane & 15;
    const int blk  = blockIdx.x;

    float bsum[12], bin[6], bhn[6];
#pragma unroll
    for (int j = 0; j < 12; ++j) { int g = wave * 192 + j * 16 + col; bsum[j] = b_ih[g] + b_hh[g]; }
#pragma unroll
    for (int j = 0; j < 6; ++j)  { int d = wave * 96 + j * 16 + col; bin[j] = b_ih[768 + d]; bhn[j] = b_hh[768 + d]; }

    // h0 = mean of child hiddens (zeros at leaf level); n-owning lanes keep h, xsum in VGPRs
    float hreg[6][4], xsum[6][4];
#pragma unroll
    for (int j = 0; j < 6; ++j) {
        int d = wave * 96 + j * 16 + col;
#pragma unroll
        for (int r = 0; r < 4; ++r) {
            int m = quad * 4 + r, gp = blk * 16 + m;
            float h0 = 0.0f;
            if (Hc != nullptr && gp < P) {
#pragma unroll
                for (int c = 0; c < 8; ++c) h0 += Hc[((size_t)(gp * 8 + c)) * 384 + d];
                h0 *= 0.125f;
            }
            hreg[j][r] = h0; xsum[j][r] = 0.0f;
            A[m][384 + d] = to_bf16(h0);
        }
    }
    // x fill for t=0 (child 7); invalid parent rows zero-filled once
    {
        int m = tid >> 4, i = tid & 15;
        int gp = blk * 16 + m;
        uint4* dst = (uint4*)&A[m][i * 24];
        if (gp < P) {
            const uint4* s = (const uint4*)(Xc + (size_t)(gp * 8 + 7) * 384 + i * 24);
            dst[0] = s[0]; dst[1] = s[1]; dst[2] = s[2];
        } else {
            uint4 z = {0u, 0u, 0u, 0u};
            dst[0] = z; dst[1] = z; dst[2] = z;
        }
    }
    __syncthreads();

    for (int t = 0; t < 8; ++t) {
        f32x4 accrz[12], accin[6], acchn[6];
#pragma unroll
        for (int j = 0; j < 12; ++j) accrz[j] = (f32x4){0.f, 0.f, 0.f, 0.f};
#pragma unroll
        for (int j = 0; j < 6; ++j) { accin[j] = (f32x4){0.f, 0.f, 0.f, 0.f}; acchn[j] = (f32x4){0.f, 0.f, 0.f, 0.f}; }

        for (int kc = 0; kc < 24; ++kc) {
            bf16x8 aF = *(const bf16x8*)&A[col][kc * 32 + quad * 8];
#pragma unroll
            for (int j = 0; j < 12; ++j) {
                int g = wave * 12 + j;
                bf16x8 bF = *(const bf16x8*)(W + ((size_t)(g * 24 + kc) * 64 + lane) * 8);
                accrz[j] = __builtin_amdgcn_mfma_f32_16x16x32_bf16(aF, bF, accrz[j], 0, 0, 0);
            }
            if (kc < 12) {
#pragma unroll
                for (int j = 0; j < 6; ++j) {
                    int g = 48 + wave * 6 + j;
                    bf16x8 bF = *(const bf16x8*)(W + ((size_t)(g * 24 + kc) * 64 + lane) * 8);
                    accin[j] = __builtin_amdgcn_mfma_f32_16x16x32_bf16(aF, bF, accin[j], 0, 0, 0);
                }
            } else {
#pragma unroll
                for (int j = 0; j < 6; ++j) {
                    int g = 48 + wave * 6 + j;
                    bf16x8 bF = *(const bf16x8*)(W + ((size_t)(g * 24 + kc) * 64 + lane) * 8);
                    acchn[j] = __builtin_amdgcn_mfma_f32_16x16x32_bf16(aF, bF, acchn[j], 0, 0, 0);
                }
            }
        }

        // epilogue 1: sigmoid(r), sigmoid(z) -> LDS
#pragma unroll
        for (int j = 0; j < 12; ++j) {
            int g = wave * 192 + j * 16 + col;
#pragma unroll
            for (int r = 0; r < 4; ++r)
                RZ[quad * 4 + r][g] = sigmoid_(accrz[j][r] + bsum[j]);
        }
        __syncthreads();

        // epilogue 2: n gate, h update; write bf16 h into A for next step
#pragma unroll
        for (int j = 0; j < 6; ++j) {
            int d = wave * 96 + j * 16 + col;
#pragma unroll
            for (int r = 0; r < 4; ++r) {
                int row = quad * 4 + r;
                float rv = RZ[row][d], zv = RZ[row][384 + d];
                float nv = tanh_(accin[j][r] + bin[j] + rv * (acchn[j][r] + bhn[j]));
                float hnew = (1.0f - zv) * nv + zv * hreg[j][r];
                hreg[j][r] = hnew; xsum[j][r] += hnew;
                A[row][384 + d] = to_bf16(hnew);
            }
        }
        // x fill for next step (child 7-(t+1))
        if (t < 7) {
            int m = tid >> 4, i = tid & 15;
            int gp = blk * 16 + m;
            if (gp < P) {
                const uint4* s = (const uint4*)(Xc + (size_t)(gp * 8 + (6 - t)) * 384 + i * 24);
                uint4* dst = (uint4*)&A[m][i * 24];
                dst[0] = s[0]; dst[1] = s[1]; dst[2] = s[2];
            }
        }
        __syncthreads();
    }

    // outputs: x_parent = mean(outs), h_parent = last h
#pragma unroll
    for (int j = 0; j < 6; ++j) {
        int d = wave * 96 + j * 16 + col;
#pragma unroll
        for (int r = 0; r < 4; ++r) {
            int gp = blk * 16 + quad * 4 + r;
            if (gp < P) {
                float xo = xsum[j][r] * 0.125f;
                Xo[(size_t)gp * 384 + d] = to_bf16(xo);
                Ho[(size_t)gp * 384 + d] = hreg[j][r];
                if (fout != nullptr) fout[d] = xo;   // only level 1 (P=1, gp==0)
            }
        }
    }
}

extern "C" void kernel_launch(void* const* d_in, const int* in_sizes, int n_in,
                              void* d_out, int out_size, void* d_ws, size_t ws_size,
                              hipStream_t stream) {
    const int*   tok   = (const int*)d_in[0];
    const float* table = (const float*)d_in[1];
    const float* w_ih  = (const float*)d_in[2];
    const float* w_hh  = (const float*)d_in[3];
    const float* b_ih  = (const float*)d_in[4];
    const float* b_hh  = (const float*)d_in[5];
    float* out = (float*)d_out;

    char* ws = (char*)d_ws;
    size_t off = 0;
    auto alloc = [&](size_t bytes) -> void* {
        void* p = ws + off;
        off = (off + bytes + 255) & ~(size_t)255;
        return p;
    };
    ushort* wswz = (ushort*)alloc((size_t)1152 * 768 * 2);
    ushort* XA   = (ushort*)alloc((size_t)32768 * 384 * 2);
    ushort* XB   = (ushort*)alloc((size_t)4096 * 384 * 2);
    ushort* XC   = (ushort*)alloc((size_t)512 * 384 * 2);
    float*  HA   = (float*)alloc((size_t)4096 * 384 * 4);
    float*  HB   = (float*)alloc((size_t)512 * 384 * 4);

    prep_w<<<(1152 * 96 + 255) / 256, 256, 0, stream>>>(w_ih, w_hh, wswz);
    embed_gather<<<(32768 * 48 + 255) / 256, 256, 0, stream>>>(tok, table, XA, 32768);

    // level 5: 4096 parents, leaf children (h=0)
    level_kernel<<<256, 256, 0, stream>>>(XA, nullptr, wswz, b_ih, b_hh, XB, HA, nullptr, 4096);
    // level 4: 512 parents
    level_kernel<<<32, 256, 0, stream>>>(XB, HA, wswz, b_ih, b_hh, XC, HB, nullptr, 512);
    // level 3: 64 parents
    level_kernel<<<4, 256, 0, stream>>>(XC, HB, wswz, b_ih, b_hh, XB, HA, nullptr, 64);
    // level 2: 8 parents
    level_kernel<<<1, 256, 0, stream>>>(XB, HA, wswz, b_ih, b_hh, XC, HB, nullptr, 8);
    // level 1: root, writes final fp32 output
    level_kernel<<<1, 256, 0, stream>>>(XC, HB, wswz, b_ih, b_hh, XB, HA, out, 1);
}